// Round 4
// baseline (206.018 us; speedup 1.0000x reference)
//
#include <hip/hip_runtime.h>
#include <stdint.h>

// Problem constants: B=32, L=8192, C=64, M=64. All I/O fp32.
#define L_     8192
#define NB     32
#define NC     64
#define SPLITK 8
#define CHUNK  (L_ / SPLITK)   // 1024

// d_out (64 MiB fp32) doubles as scratch for k0..k2; k3 overwrites all of it
// and reads none of it (TF bridged through the dead wr input buffer by k2b).
#define BF_OFF 0            // Bf table:    128 x 8192 bf16 = 2 MiB
#define XF_OFF (2u  << 20)  // XF partials: 8 x 32 x 128 x 64 fp32 = 8 MiB
#define TF_OFF (10u << 20)  // TF staging:  32 x 64 x 192 bf16 = 768 KiB

typedef __bf16 bf16x8 __attribute__((ext_vector_type(8)));
typedef float  f32x4  __attribute__((ext_vector_type(4)));
typedef short  s16x8  __attribute__((ext_vector_type(8)));

__device__ __forceinline__ unsigned short f2bf(float f) {
  union { float f; unsigned int i; } v; v.f = f;
  unsigned int r = v.i + 0x7fffu + ((v.i >> 16) & 1u);  // RNE
  return (unsigned short)(r >> 16);
}
__device__ __forceinline__ f32x4 mfma16(bf16x8 a, bf16x8 b, f32x4 c) {
  return __builtin_amdgcn_mfma_f32_16x16x32_bf16(a, b, c, 0, 0, 0);
}

// ---------------------------------------------------------------------------
// k0: forward DFT basis Bf[j][l] (bf16): j=2k: a_k cos(2pi k l/L), j=2k+1:
// -a_k sin. a_k = (k==0?1:2)/L folds the irfft normalization forward.
// ---------------------------------------------------------------------------
__global__ __launch_bounds__(256) void k0_bf(unsigned short* __restrict__ Bf) {
  const int e0 = (blockIdx.x * 256 + threadIdx.x) * 4;
  const float W0 = 6.283185307179586f / 8192.0f;
  #pragma unroll
  for (int u = 0; u < 4; ++u) {
    const int e = e0 + u;
    const int j = e >> 13, l = e & 8191, k = j >> 1;
    const float th = (float)((k * l) & 8191) * W0;   // exact int phase reduction
    float sv, cv; __sincosf(th, &sv, &cv);
    const float a = (k == 0 ? 1.0f : 2.0f) * (1.0f / 8192.0f);
    Bf[e] = f2bf((j & 1) ? (-a * sv) : (a * cv));
  }
}

// ---------------------------------------------------------------------------
// k1: per (b, chunk p): XF[p][b][128][64] = Bf[128][chunk] @ x_bf16[b][chunk][64]
// x is fp32; B-fragments are built from 8 strided scalar loads + RNE cvt.
// ---------------------------------------------------------------------------
__global__ __launch_bounds__(256) void k1_dft(const float* __restrict__ x,
                                              const unsigned short* __restrict__ Bf,
                                              float* __restrict__ XFP) {
  const int b = blockIdx.x >> 3;
  const int p = blockIdx.x & 7;
  const int wv = threadIdx.x >> 6;
  const int lane = threadIdx.x & 63;
  const int q = lane >> 4;
  const int n = lane & 15;
  const int c0 = wv * 16;
  const float* xb = x + (size_t)b * L_ * NC;
  f32x4 acc[8];
  #pragma unroll
  for (int i = 0; i < 8; ++i) acc[i] = (f32x4){0.f, 0.f, 0.f, 0.f};
  const int l0 = p * CHUNK;
  for (int ks = 0; ks < CHUNK; ks += 32) {
    const int lb = l0 + ks + q * 8;
    s16x8 bs;
    #pragma unroll
    for (int j = 0; j < 8; ++j)              // B-frag: l-strided fp32 loads
      bs[j] = (short)f2bf(xb[(size_t)(lb + j) * NC + c0 + n]);
    const bf16x8 bfrag = __builtin_bit_cast(bf16x8, bs);
    #pragma unroll
    for (int mt = 0; mt < 8; ++mt) {         // A-frag: contiguous 16B from Bf
      const bf16x8 afrag = *(const bf16x8*)(Bf + (size_t)(mt * 16 + n) * L_ + lb);
      acc[mt] = mfma16(afrag, bfrag, acc[mt]);
    }
  }
  float* op = XFP + (size_t)(p * NB + b) * 128 * NC;
  #pragma unroll
  for (int mt = 0; mt < 8; ++mt)
    #pragma unroll
    for (int r = 0; r < 4; ++r)
      op[(size_t)(mt * 16 + q * 4 + r) * NC + c0 + n] = acc[mt][r];
}

// ---------------------------------------------------------------------------
// k2: block (b, og): sum split-K partials into LDS (transposed to [chan][mode],
// stride 65 = conflict-free), complex mode-mix TF[o][m] = sum_i XF[i][m]W[i][o][m],
// write packed re/im bf16 pairs + pw rows to TF staging (row = 192 bf16 / 96 u32).
// ---------------------------------------------------------------------------
__global__ __launch_bounds__(256) void k2_mix(const float* __restrict__ XFP,
                                              const float* __restrict__ wr,
                                              const float* __restrict__ wi,
                                              const float* __restrict__ pww,
                                              uint32_t* __restrict__ tf_stage) {
  const int b = blockIdx.x >> 3;
  const int og = blockIdx.x & 7;
  const int t = threadIdx.x;
  __shared__ float sxr[64 * 65];   // [chan i][mode m], +1 pad
  __shared__ float sxi[64 * 65];
  for (int e = t; e < 8192; e += 256) {      // e = j*64 + c, j = 2m+reim
    float s = 0.f;
    #pragma unroll
    for (int p = 0; p < SPLITK; ++p) s += XFP[(size_t)(p * NB + b) * 8192 + e];
    const int j = e >> 6, c = e & 63, m = j >> 1;
    if (j & 1) sxi[c * 65 + m] = s; else sxr[c * 65 + m] = s;
  }
  __syncthreads();
  const int k = t & 63;        // mode (lane)
  const int wv = t >> 6;
  #pragma unroll
  for (int oo = 0; oo < 2; ++oo) {
    const int o = og * 8 + wv * 2 + oo;
    float ar = 0.f, ai = 0.f;
    #pragma unroll 8
    for (int i = 0; i < 64; ++i) {           // input channel
      const float xr  = sxr[i * 65 + k];
      const float xi_ = sxi[i * 65 + k];
      const float wrv = wr[(size_t)i * 4096 + o * 64 + k];
      const float wiv = wi[(size_t)i * 4096 + o * 64 + k];
      ar = fmaf(xr, wrv, ar);  ar = fmaf(-xi_, wiv, ar);
      ai = fmaf(xr, wiv, ai);  ai = fmaf(xi_, wrv, ai);
    }
    uint32_t* row = tf_stage + ((size_t)b * 64 + o) * 96;
    row[k] = (uint32_t)f2bf(ar) | ((uint32_t)f2bf(ai) << 16);
    if (k < 32)                               // pw rows: bf16 pairs [64..96)
      row[64 + k] = (uint32_t)f2bf(pww[o * 64 + 2 * k]) |
                    ((uint32_t)f2bf(pww[o * 64 + 2 * k + 1]) << 16);
  }
}

// ---------------------------------------------------------------------------
// k2b: bridge TF staging (768 KiB in d_out) into the dead wr input buffer
// (1 MiB) so k3 never reads d_out.
// ---------------------------------------------------------------------------
__global__ __launch_bounds__(256) void k2b_copy(const uint4* __restrict__ src,
                                                uint4* __restrict__ dst) {
  const int idx = blockIdx.x * 256 + threadIdx.x;   // 49152 uint4 = 768 KiB
  dst[idx] = src[idx];
}

// ---------------------------------------------------------------------------
// k3: out[b][8192][64] = [Bi_onfly | x_bf16[b]] (8192x192) @ TF[b] (192x64)^T
// + bias. Bi via __sincosf per fragment (each element used exactly once).
// ---------------------------------------------------------------------------
__global__ __launch_bounds__(256) void k3_out(const float* __restrict__ x,
                                              const unsigned short* __restrict__ tf,
                                              const float* __restrict__ bias,
                                              float* __restrict__ out) {
  const int b = blockIdx.x >> 6;
  const int lt = blockIdx.x & 63;
  const int wv = threadIdx.x >> 6;
  const int lane = threadIdx.x & 63;
  const int q = lane >> 4;
  const int n = lane & 15;
  const int l0 = lt * 128 + wv * 32;   // wave: 32 rows (2 m-tiles) x 64 cols
  const float* xb = x + (size_t)b * L_ * NC;
  const unsigned short* tfb = tf + (size_t)b * 64 * 192;
  const float W0 = 6.283185307179586f / 8192.0f;
  f32x4 acc[2][4];
  #pragma unroll
  for (int i = 0; i < 2; ++i)
    #pragma unroll
    for (int j = 0; j < 4; ++j) acc[i][j] = (f32x4){0.f, 0.f, 0.f, 0.f};
  const int la  = l0 + n;        // row for a0
  const int lb2 = l0 + 16 + n;   // row for a1
  #pragma unroll
  for (int s = 0; s < 6; ++s) {
    const int k0 = s * 32;
    bf16x8 a0, a1;
    if (s < 4) {                 // spectral: Bi[l][kk] on the fly
      s16x8 t0, t1;
      #pragma unroll
      for (int jj = 0; jj < 4; ++jj) {
        const int kf = (k0 >> 1) + q * 4 + jj;
        float sv, cv;
        __sincosf((float)((kf * la) & 8191) * W0, &sv, &cv);
        t0[2 * jj] = (short)f2bf(cv); t0[2 * jj + 1] = (short)f2bf(-sv);
        __sincosf((float)((kf * lb2) & 8191) * W0, &sv, &cv);
        t1[2 * jj] = (short)f2bf(cv); t1[2 * jj + 1] = (short)f2bf(-sv);
      }
      a0 = __builtin_bit_cast(bf16x8, t0);
      a1 = __builtin_bit_cast(bf16x8, t1);
    } else {                     // pointwise: x rows (c contiguous fp32 + cvt)
      const int cc = (k0 - 128) + q * 8;
      s16x8 t0, t1;
      #pragma unroll
      for (int j = 0; j < 8; ++j) {
        t0[j] = (short)f2bf(xb[(size_t)la  * NC + cc + j]);
        t1[j] = (short)f2bf(xb[(size_t)lb2 * NC + cc + j]);
      }
      a0 = __builtin_bit_cast(bf16x8, t0);
      a1 = __builtin_bit_cast(bf16x8, t1);
    }
    #pragma unroll
    for (int nt = 0; nt < 4; ++nt) {
      const bf16x8 bfrag = *(const bf16x8*)(tfb + (size_t)(nt * 16 + n) * 192 + k0 + q * 8);
      acc[0][nt] = mfma16(a0, bfrag, acc[0][nt]);
      acc[1][nt] = mfma16(a1, bfrag, acc[1][nt]);
    }
  }
  float* ob = out + (size_t)b * L_ * NC;
  #pragma unroll
  for (int nt = 0; nt < 4; ++nt) {
    const float bv = bias[nt * 16 + n];
    #pragma unroll
    for (int mt = 0; mt < 2; ++mt)
      #pragma unroll
      for (int r = 0; r < 4; ++r) {
        const int row = l0 + mt * 16 + q * 4 + r;
        ob[(size_t)row * NC + nt * 16 + n] = acc[mt][nt][r] + bv;
      }
  }
}

// ---------------------------------------------------------------------------
extern "C" void kernel_launch(void* const* d_in, const int* in_sizes, int n_in,
                              void* d_out, int out_size, void* d_ws, size_t ws_size,
                              hipStream_t stream) {
  (void)in_sizes; (void)n_in; (void)out_size; (void)d_ws; (void)ws_size;
  const float* x    = (const float*)d_in[0];
  float*       wr   = (float*)d_in[1];        // dead after k2 -> TF bridge
  const float* wi   = (const float*)d_in[2];
  const float* pww  = (const float*)d_in[3];
  const float* bias = (const float*)d_in[4];
  float* out = (float*)d_out;

  char* ob = (char*)d_out;
  unsigned short* Bf  = (unsigned short*)(ob + BF_OFF);
  float*          XFP = (float*)(ob + XF_OFF);
  uint32_t*       TFS = (uint32_t*)(ob + TF_OFF);

  k0_bf   <<<1024,        256, 0, stream>>>(Bf);
  k1_dft  <<<NB * SPLITK, 256, 0, stream>>>(x, Bf, XFP);
  k2_mix  <<<NB * 8,      256, 0, stream>>>(XFP, wr, wi, pww, TFS);
  k2b_copy<<<192,         256, 0, stream>>>((const uint4*)TFS, (uint4*)wr);
  k3_out  <<<NB * 64,     256, 0, stream>>>(x, (const unsigned short*)wr, bias, out);
}